// Round 1
// 247.161 us; speedup vs baseline: 1.0352x; 1.0352x over previous
//
#include <hip/hip_runtime.h>

#define NBLOCKS 2048
#define NTHREADS 256
#define UNROLL 8   // 8 vec4 per stream per chunk iteration

typedef float vfloat4 __attribute__((ext_vector_type(4)));

#if defined(__has_builtin)
#  if __has_builtin(__builtin_amdgcn_sched_barrier)
#    define SCHED_FENCE() __builtin_amdgcn_sched_barrier(0)
#  endif
#endif
#ifndef SCHED_FENCE
#  define SCHED_FENCE()
#endif

// Streaming pass: identical main loop to the 255.9 µs kernel, but the block
// result goes to a distinct partial[blockIdx.x] slot (plain store) instead of
// 2048 same-address device-scope atomicAdds — removes the serialized TCC
// drain tail and the need to pre-zero the output.
__global__ __launch_bounds__(NTHREADS, 4) void l1_partial_kernel(
    const vfloat4* __restrict__ a, const vfloat4* __restrict__ b,
    const float* __restrict__ af, const float* __restrict__ bf,
    float* __restrict__ partial, long n4, long n_total) {
    const int tid = threadIdx.x;
    const long chunk = (long)NTHREADS * UNROLL;   // 2048 vec4 (32 KB) per block-chunk
    const long nchunks = n4 / chunk;

    float acc[UNROLL];
    #pragma unroll
    for (int j = 0; j < UNROLL; ++j) acc[j] = 0.f;

    for (long c = blockIdx.x; c < nchunks; c += NBLOCKS) {
        const long base = c * chunk + tid;
        vfloat4 xs[UNROLL], ys[UNROLL];
        // Nontemporal: nt policy bypasses L1 allocation (deeper L2 queues),
        // avoids thrashing the exactly-256MiB L3 working set.
        #pragma unroll
        for (int j = 0; j < UNROLL; ++j)
            xs[j] = __builtin_nontemporal_load(&a[base + j * NTHREADS]);
        #pragma unroll
        for (int j = 0; j < UNROLL; ++j)
            ys[j] = __builtin_nontemporal_load(&b[base + j * NTHREADS]);
        SCHED_FENCE();
        #pragma unroll
        for (int j = 0; j < UNROLL; ++j) {
            vfloat4 d = xs[j] - ys[j];
            acc[j] += fabsf(d.x) + fabsf(d.y) + fabsf(d.z) + fabsf(d.w);
        }
    }

    // remainder vec4s not covered by full chunks (none for this shape)
    float racc = 0.f;
    const long gid = (long)blockIdx.x * NTHREADS + tid;
    const long tthreads = (long)NBLOCKS * NTHREADS;
    for (long i = nchunks * chunk + gid; i < n4; i += tthreads) {
        vfloat4 x = a[i], y = b[i];
        racc += fabsf(x.x - y.x) + fabsf(x.y - y.y)
              + fabsf(x.z - y.z) + fabsf(x.w - y.w);
    }
    // scalar tail for n % 4 (none for this shape)
    for (long e = n4 * 4 + gid; e < n_total; e += tthreads)
        racc += fabsf(af[e] - bf[e]);

    float acc_total = ((acc[0] + acc[1]) + (acc[2] + acc[3]))
                    + ((acc[4] + acc[5]) + (acc[6] + acc[7])) + racc;

    #pragma unroll
    for (int off = 32; off > 0; off >>= 1)
        acc_total += __shfl_down(acc_total, off, 64);

    __shared__ float smem[NTHREADS / 64];
    int wave = tid >> 6;
    int lane = tid & 63;
    if (lane == 0) smem[wave] = acc_total;
    __syncthreads();
    if (tid == 0) {
        float s = 0.f;
        #pragma unroll
        for (int w = 0; w < NTHREADS / 64; ++w) s += smem[w];
        partial[blockIdx.x] = s;   // distinct address per block — no atomic, no contention
    }
}

// Tiny reduce: 1 block folds the 2048 partials (8 KB, L2-hot from the main
// kernel) and writes the final mean. Replaces the old hipMemsetAsync node, so
// the graph node count is unchanged. Kernel-boundary ordering on the stream
// makes the partials coherent device-wide (no fences needed).
__global__ __launch_bounds__(NTHREADS, 1) void l1_reduce_kernel(
    const float* __restrict__ partial, float* __restrict__ out, float inv_n) {
    const int tid = threadIdx.x;
    float s = 0.f;
    #pragma unroll
    for (int j = 0; j < NBLOCKS / NTHREADS; ++j)
        s += partial[tid + j * NTHREADS];
    #pragma unroll
    for (int off = 32; off > 0; off >>= 1)
        s += __shfl_down(s, off, 64);
    __shared__ float smem[NTHREADS / 64];
    int wave = tid >> 6;
    int lane = tid & 63;
    if (lane == 0) smem[wave] = s;
    __syncthreads();
    if (tid == 0) {
        float t = 0.f;
        #pragma unroll
        for (int w = 0; w < NTHREADS / 64; ++w) t += smem[w];
        out[0] = t * inv_n;   // full overwrite — poisoned d_out needs no memset
    }
}

extern "C" void kernel_launch(void* const* d_in, const int* in_sizes, int n_in,
                              void* d_out, int out_size, void* d_ws, size_t ws_size,
                              hipStream_t stream) {
    const float* yhat = (const float*)d_in[0];
    const float* y    = (const float*)d_in[1];
    float* out = (float*)d_out;
    float* partial = (float*)d_ws;   // 2048 floats = 8 KB of workspace

    long n = (long)in_sizes[0];
    long n4 = n / 4;
    float inv_n = 1.0f / (float)n;

    l1_partial_kernel<<<NBLOCKS, NTHREADS, 0, stream>>>(
        (const vfloat4*)yhat, (const vfloat4*)y, yhat, y, partial, n4, n);
    l1_reduce_kernel<<<1, NTHREADS, 0, stream>>>(partial, out, inv_n);
}